// Round 1
// 2426.464 us; speedup vs baseline: 2.4610x; 2.4610x over previous
//
#include <hip/hip_runtime.h>
#include <hip/hip_bf16.h>

typedef __hip_bfloat16 bf16;

#define B_  4
#define NT_ 1024
#define NS_ 1024
#define D_  512
#define E_  512
#define H_  8
#define HD_ 64
#define FF_ 2048
#define RH_ 16

__device__ int g_flag;   // 0 = bf16 tensors, 1 = fp32 tensors

__device__ __forceinline__ float b2f(bf16 x) { return __bfloat162float(x); }

__device__ __forceinline__ float2 upair(unsigned int u) {
  union { unsigned int i; float f; } lo, hi;
  lo.i = u << 16;
  hi.i = u & 0xffff0000u;
  return make_float2(lo.f, hi.f);
}

__device__ __forceinline__ unsigned short f2b_bits(float f) {
  union { bf16 h; unsigned short s; } u;
  u.h = __float2bfloat16(f);
  return u.s;
}

__device__ __forceinline__ unsigned int packbf(float a, float b) {
  return (unsigned int)f2b_bits(a) | ((unsigned int)f2b_bits(b) << 16);
}

template <typename T> struct TypeTag;
template <> struct TypeTag<float> { static constexpr int v = 1; };
template <> struct TypeTag<bf16>  { static constexpr int v = 0; };

template <typename T> __device__ __forceinline__ float ld1(const T* p);
template <> __device__ __forceinline__ float ld1<float>(const float* p) { return *p; }
template <> __device__ __forceinline__ float ld1<bf16>(const bf16* p) { return b2f(*p); }

template <typename T> __device__ __forceinline__ float2 ld2(const T* p);
template <> __device__ __forceinline__ float2 ld2<float>(const float* p) { return *(const float2*)p; }
template <> __device__ __forceinline__ float2 ld2<bf16>(const bf16* p) { return upair(*(const unsigned int*)p); }

template <typename T> __device__ __forceinline__ void st2(T* p, float a, float b);
template <> __device__ __forceinline__ void st2<float>(float* p, float a, float b) { *(float2*)p = make_float2(a, b); }
template <> __device__ __forceinline__ void st2<bf16>(bf16* p, float a, float b) { *(unsigned int*)p = packbf(a, b); }

// ---- detector: fp32 inputs leave random-exponent garbage when read as bf16 ---
__global__ void detect_kernel(const unsigned int* __restrict__ xt_raw) {
  __shared__ int bad;
  if (threadIdx.x == 0) bad = 0;
  __syncthreads();
  int t = threadIdx.x;
  int local = 0;
  for (int i = 0; i < 8; ++i) {
    float2 v = upair(xt_raw[t * 8 + i]);
    if (!(fabsf(v.x) <= 1e8f)) local = 1;
    if (!(fabsf(v.y) <= 1e8f)) local = 1;
  }
  if (local) atomicOr(&bad, 1);
  __syncthreads();
  if (t == 0) g_flag = bad;
}

// ---------------- RPE part 1: b_emb (needed by attention) ---------------------
template <typename T>
__global__ void rpe_bemb_kernel(const T* __restrict__ coords,
                                const T* __restrict__ W1, const T* __restrict__ b1,
                                const T* __restrict__ W2, T* __restrict__ b_emb) {
  if (g_flag != TypeTag<T>::v) return;
  __shared__ float sW1[32], sb1[16], sW2[128];
  int tid = threadIdx.x;
  if (tid < 32)  sW1[tid] = ld1(W1 + tid);
  if (tid < 16)  sb1[tid] = ld1(b1 + tid);
  if (tid < 128) sW2[tid] = ld1(W2 + tid);
  __syncthreads();
  size_t idx = (size_t)blockIdx.x * 256 + tid;
  float2 c = ld2(coords + idx * 2);
  float h[16];
#pragma unroll
  for (int j = 0; j < 16; ++j) {
    float t = fmaf(c.x, sW1[j], fmaf(c.y, sW1[16 + j], sb1[j]));
    h[j] = t > 0.f ? t : 0.f;
  }
  float acc[8] = {0.f, 0.f, 0.f, 0.f, 0.f, 0.f, 0.f, 0.f};
#pragma unroll
  for (int j = 0; j < 16; ++j) {
    float hv = h[j];
#pragma unroll
    for (int n = 0; n < 8; ++n) acc[n] = fmaf(hv, sW2[j * 8 + n], acc[n]);
  }
  T* bp = b_emb + idx * 8;
#pragma unroll
  for (int j = 0; j < 4; ++j) st2(bp + 2 * j, acc[2 * j], acc[2 * j + 1]);
}

// ---------------- RPE part 2: rel_emb (runs LAST; overwrites scratch) ---------
template <typename T>
__global__ void rpe_rel_kernel(const T* __restrict__ coords,
                               const T* __restrict__ W1, const T* __restrict__ b1,
                               T* __restrict__ rel_emb) {
  if (g_flag != TypeTag<T>::v) return;
  __shared__ float sW1[32], sb1[16];
  int tid = threadIdx.x;
  if (tid < 32)  sW1[tid] = ld1(W1 + tid);
  if (tid < 16)  sb1[tid] = ld1(b1 + tid);
  __syncthreads();
  size_t idx = (size_t)blockIdx.x * 256 + tid;
  float2 c = ld2(coords + idx * 2);
  T* rp = rel_emb + idx * 16;
#pragma unroll
  for (int j = 0; j < 16; j += 2) {
    float t0 = fmaf(c.x, sW1[j], fmaf(c.y, sW1[16 + j], sb1[j]));
    float t1 = fmaf(c.x, sW1[j + 1], fmaf(c.y, sW1[16 + j + 1], sb1[j + 1]));
    st2(rp + j, t0 > 0.f ? t0 : 0.f, t1 > 0.f ? t1 : 0.f);
  }
}

// ---------------- projection + per-head normalize (+scale for q) --------------
// MT=4 rows per block: weight panel L2 traffic /4, 4 FMAs per weight load.
// mode: 0 = v, 1 = k (normalize), 2 = q (normalize * exp(min(ls,log100)))
template <typename T>
__global__ void proj_kernel(const T* __restrict__ X, const T* __restrict__ W,
                            const T* __restrict__ bias, const T* __restrict__ lsc,
                            float* __restrict__ out, int mode) {
  if (g_flag != TypeTag<T>::v) return;
  __shared__ float xrow[4][512];
  __shared__ float hs[4][8];
  int tid = threadIdx.x;
  int m0 = blockIdx.x * 4;
#pragma unroll
  for (int r = 0; r < 4; ++r) {
    float2 xv = ld2(X + (size_t)(m0 + r) * 512 + 2 * tid);
    *(float2*)(&xrow[r][2 * tid]) = xv;
  }
  __syncthreads();
  int n0 = 2 * tid;
  float acc[4][2] = {};
#pragma unroll 2
  for (int k = 0; k < 512; ++k) {
    float2 wv = ld2(W + (size_t)k * 512 + n0);
#pragma unroll
    for (int r = 0; r < 4; ++r) {
      acc[r][0] = fmaf(xrow[r][k], wv.x, acc[r][0]);
      acc[r][1] = fmaf(xrow[r][k], wv.y, acc[r][1]);
    }
  }
  {
    float2 bv = ld2(bias + n0);
#pragma unroll
    for (int r = 0; r < 4; ++r) { acc[r][0] += bv.x; acc[r][1] += bv.y; }
  }
  if (mode > 0) {
    __syncthreads();  // all xrow reads done; safe to overwrite with proj output
#pragma unroll
    for (int r = 0; r < 4; ++r) {
      xrow[r][n0] = acc[r][0];
      xrow[r][n0 + 1] = acc[r][1];
    }
    __syncthreads();
    if (tid < 32) {
      int r = tid >> 3, hh = tid & 7;
      float s = 0.f;
      for (int i = 0; i < 64; ++i) { float t = xrow[r][hh * 64 + i]; s = fmaf(t, t, s); }
      float rr = 1.0f / sqrtf(s + 1e-12f);
      if (mode == 2) rr *= expf(fminf(ld1(lsc + hh), 4.60517018598809f));
      hs[r][hh] = rr;
    }
    __syncthreads();
    int hh = n0 >> 6;
#pragma unroll
    for (int r = 0; r < 4; ++r) { acc[r][0] *= hs[r][hh]; acc[r][1] *= hs[r][hh]; }
  }
  int hh = n0 >> 6, d = n0 & 63;
#pragma unroll
  for (int r = 0; r < 4; ++r) {
    int m = m0 + r;
    int b = m >> 10, row = m & 1023;
    float* op = out + ((((size_t)b * H_ + hh) * 1024 + row) * 64 + d);
    *(float2*)op = make_float2(acc[r][0], acc[r][1]);
  }
}

// ---------------- attention: one block per (b,h, 16-q-row tile) ---------------
// LDS: sc[16][1024] score tile (64KB); Q tile aliases sc[0..1023] during QK.
template <typename T>
__global__ void attn_kernel(const float* __restrict__ qn, const float* __restrict__ kn,
                            const float* __restrict__ vv, const T* __restrict__ bemb,
                            T* __restrict__ att, float* __restrict__ ctx) {
  if (g_flag != TypeTag<T>::v) return;
  __shared__ float sc[16 * 1024];
  int tid = threadIdx.x;
  int qt0 = blockIdx.x * 16;
  int h = blockIdx.y, b = blockIdx.z;
  size_t bh = (size_t)b * H_ + h;

  // phase 1: Q tile (16 rows x 64) -> sc[0..1023]
  {
    const float4* qp = (const float4*)(qn + (bh * 1024 + qt0) * 64);
    ((float4*)sc)[tid] = qp[tid];
  }
  __syncthreads();

  // phase 2: scores. thread owns k in {tid, tid+256, tid+512, tid+768}
  float acc[16][4];
#pragma unroll
  for (int q = 0; q < 16; ++q)
#pragma unroll
    for (int i = 0; i < 4; ++i) acc[q][i] = 0.f;
  const float* kb = kn + bh * 65536;
#pragma unroll 4
  for (int dc = 0; dc < 16; ++dc) {
    float4 kv[4];
#pragma unroll
    for (int i = 0; i < 4; ++i)
      kv[i] = *(const float4*)(kb + (size_t)(tid + 256 * i) * 64 + dc * 4);
#pragma unroll
    for (int q = 0; q < 16; ++q) {
      float4 qv = *(const float4*)(sc + q * 64 + dc * 4);  // broadcast
#pragma unroll
      for (int i = 0; i < 4; ++i) {
        acc[q][i] = fmaf(qv.x, kv[i].x, acc[q][i]);
        acc[q][i] = fmaf(qv.y, kv[i].y, acc[q][i]);
        acc[q][i] = fmaf(qv.z, kv[i].z, acc[q][i]);
        acc[q][i] = fmaf(qv.w, kv[i].w, acc[q][i]);
      }
    }
  }
  // add b_emb
  {
    const T* bb = bemb + ((size_t)(b * 1024 + qt0) * 1024) * 8 + h;
#pragma unroll
    for (int q = 0; q < 16; ++q)
#pragma unroll
      for (int i = 0; i < 4; ++i)
        acc[q][i] += ld1(bb + ((size_t)q * 1024 + tid + 256 * i) * 8);
  }
  __syncthreads();  // all Q reads done; overwrite sc with scores
#pragma unroll
  for (int q = 0; q < 16; ++q)
#pragma unroll
    for (int i = 0; i < 4; ++i) sc[q * 1024 + tid + 256 * i] = acc[q][i];
  __syncthreads();

  // phase 3: row softmax. 16 threads per row, shfl reductions (same wave).
  {
    int r = tid >> 4, j = tid & 15;
    float* srow = sc + r * 1024;
    float mx = -1e30f;
#pragma unroll 8
    for (int m = 0; m < 64; ++m) mx = fmaxf(mx, srow[j + 16 * m]);
#pragma unroll
    for (int off = 8; off >= 1; off >>= 1) mx = fmaxf(mx, __shfl_xor(mx, off));
    float sum = 0.f;
#pragma unroll 8
    for (int m = 0; m < 64; ++m) {
      float p = __expf(srow[j + 16 * m] - mx);
      srow[j + 16 * m] = p;
      sum += p;
    }
#pragma unroll
    for (int off = 8; off >= 1; off >>= 1) sum += __shfl_xor(sum, off);
    float inv = 1.0f / sum;
#pragma unroll 8
    for (int m = 0; m < 64; ++m) srow[j + 16 * m] *= inv;
  }
  __syncthreads();

  // phase 4a: write att tile (coalesced pair stores)
  {
    T* ap = att + (bh * 1024 + qt0) * 1024;
#pragma unroll
    for (int w = 0; w < 32; ++w) {
      int f = 2 * (w * 256 + tid);
      float2 pv = *(const float2*)(sc + f);
      st2(ap + f, pv.x, pv.y);
    }
  }

  // phase 4b: PV. wave gq owns q rows 4*gq..4*gq+3; lane owns d.
  {
    int d = tid & 63, gq = tid >> 6;
    const float* vb = vv + bh * 65536;
    const float* p0 = sc + (4 * gq + 0) * 1024;
    const float* p1 = sc + (4 * gq + 1) * 1024;
    const float* p2 = sc + (4 * gq + 2) * 1024;
    const float* p3 = sc + (4 * gq + 3) * 1024;
    float a0 = 0.f, a1 = 0.f, a2 = 0.f, a3 = 0.f;
    for (int k = 0; k < 1024; k += 4) {
      float4 q0 = *(const float4*)(p0 + k);
      float4 q1 = *(const float4*)(p1 + k);
      float4 q2 = *(const float4*)(p2 + k);
      float4 q3 = *(const float4*)(p3 + k);
      float v0 = vb[(size_t)(k + 0) * 64 + d];
      float v1 = vb[(size_t)(k + 1) * 64 + d];
      float v2 = vb[(size_t)(k + 2) * 64 + d];
      float v3 = vb[(size_t)(k + 3) * 64 + d];
      a0 = fmaf(q0.w, v3, fmaf(q0.z, v2, fmaf(q0.y, v1, fmaf(q0.x, v0, a0))));
      a1 = fmaf(q1.w, v3, fmaf(q1.z, v2, fmaf(q1.y, v1, fmaf(q1.x, v0, a1))));
      a2 = fmaf(q2.w, v3, fmaf(q2.z, v2, fmaf(q2.y, v1, fmaf(q2.x, v0, a2))));
      a3 = fmaf(q3.w, v3, fmaf(q3.z, v2, fmaf(q3.y, v1, fmaf(q3.x, v0, a3))));
    }
    float* cb = ctx + ((size_t)b * 1024 + qt0 + 4 * gq) * 512 + h * 64 + d;
    cb[0] = a0;
    cb[512] = a1;
    cb[1024] = a2;
    cb[1536] = a3;
  }
}

// ---------------- out-proj + bias + residual + LayerNorm1 (MT=4) --------------
template <typename T>
__global__ void oproj_ln(const float* __restrict__ ctx, const T* __restrict__ Wo,
                         const T* __restrict__ bo, const T* __restrict__ xt,
                         const T* __restrict__ g, const T* __restrict__ bta,
                         float* __restrict__ xout) {
  if (g_flag != TypeTag<T>::v) return;
  __shared__ float xrow[4][512];
  __shared__ float red[4][4];
  int tid = threadIdx.x, m0 = blockIdx.x * 4;
#pragma unroll
  for (int r = 0; r < 4; ++r)
    *(float2*)(&xrow[r][2 * tid]) = *(const float2*)(ctx + (size_t)(m0 + r) * 512 + 2 * tid);
  __syncthreads();
  int n0 = 2 * tid;
  float acc[4][2] = {};
#pragma unroll 2
  for (int k = 0; k < 512; ++k) {
    float2 wv = ld2(Wo + (size_t)k * 512 + n0);
#pragma unroll
    for (int r = 0; r < 4; ++r) {
      acc[r][0] = fmaf(xrow[r][k], wv.x, acc[r][0]);
      acc[r][1] = fmaf(xrow[r][k], wv.y, acc[r][1]);
    }
  }
  float2 bv = ld2(bo + n0);
  float x0[4], x1[4];
#pragma unroll
  for (int r = 0; r < 4; ++r) {
    float2 xv = ld2(xt + (size_t)(m0 + r) * 512 + n0);
    x0[r] = acc[r][0] + bv.x + xv.x;
    x1[r] = acc[r][1] + bv.y + xv.y;
  }
  int lane = tid & 63, wid = tid >> 6;
  float s[4];
#pragma unroll
  for (int r = 0; r < 4; ++r) s[r] = x0[r] + x1[r];
#pragma unroll
  for (int off = 32; off >= 1; off >>= 1)
#pragma unroll
    for (int r = 0; r < 4; ++r) s[r] += __shfl_xor(s[r], off);
  if (lane == 0) {
#pragma unroll
    for (int r = 0; r < 4; ++r) red[r][wid] = s[r];
  }
  __syncthreads();
  float mu[4];
#pragma unroll
  for (int r = 0; r < 4; ++r) mu[r] = (red[r][0] + red[r][1] + red[r][2] + red[r][3]) * (1.0f / 512.0f);
  __syncthreads();
  float d0[4], d1[4];
#pragma unroll
  for (int r = 0; r < 4; ++r) {
    d0[r] = x0[r] - mu[r];
    d1[r] = x1[r] - mu[r];
    s[r] = d0[r] * d0[r] + d1[r] * d1[r];
  }
#pragma unroll
  for (int off = 32; off >= 1; off >>= 1)
#pragma unroll
    for (int r = 0; r < 4; ++r) s[r] += __shfl_xor(s[r], off);
  if (lane == 0) {
#pragma unroll
    for (int r = 0; r < 4; ++r) red[r][wid] = s[r];
  }
  __syncthreads();
  float2 gv = ld2(g + n0);
  float2 btv = ld2(bta + n0);
#pragma unroll
  for (int r = 0; r < 4; ++r) {
    float rstd = 1.0f / sqrtf((red[r][0] + red[r][1] + red[r][2] + red[r][3]) * (1.0f / 512.0f) + 1e-5f);
    float* op = xout + (size_t)(m0 + r) * 512 + n0;
    op[0] = d0[r] * rstd * gv.x + btv.x;
    op[1] = d1[r] * rstd * gv.y + btv.y;
  }
}

// ---------------- fused MLP + residual + LN2 -> out (MT=4) --------------------
template <typename T>
__global__ void mlp_fused(const float* __restrict__ xin, const T* __restrict__ W1,
                          const T* __restrict__ b1, const T* __restrict__ W2,
                          const T* __restrict__ b2, const T* __restrict__ g,
                          const T* __restrict__ bt, T* __restrict__ out) {
  if (g_flag != TypeTag<T>::v) return;
  __shared__ float xrow[4][512];
  __shared__ float hrow[4][2048];
  __shared__ float red[4][4];
  int tid = threadIdx.x, m0 = blockIdx.x * 4;
#pragma unroll
  for (int r = 0; r < 4; ++r)
    *(float2*)(&xrow[r][2 * tid]) = *(const float2*)(xin + (size_t)(m0 + r) * 512 + 2 * tid);
  __syncthreads();
  float acc[4][8] = {};
  for (int k = 0; k < 512; ++k) {
    const T* wr = W1 + (size_t)k * 2048;
    float xv0 = xrow[0][k], xv1 = xrow[1][k], xv2 = xrow[2][k], xv3 = xrow[3][k];
#pragma unroll
    for (int j = 0; j < 4; ++j) {
      float2 wv = ld2(wr + 2 * tid + j * 512);
      acc[0][2 * j] = fmaf(xv0, wv.x, acc[0][2 * j]);
      acc[0][2 * j + 1] = fmaf(xv0, wv.y, acc[0][2 * j + 1]);
      acc[1][2 * j] = fmaf(xv1, wv.x, acc[1][2 * j]);
      acc[1][2 * j + 1] = fmaf(xv1, wv.y, acc[1][2 * j + 1]);
      acc[2][2 * j] = fmaf(xv2, wv.x, acc[2][2 * j]);
      acc[2][2 * j + 1] = fmaf(xv2, wv.y, acc[2][2 * j + 1]);
      acc[3][2 * j] = fmaf(xv3, wv.x, acc[3][2 * j]);
      acc[3][2 * j + 1] = fmaf(xv3, wv.y, acc[3][2 * j + 1]);
    }
  }
#pragma unroll
  for (int j = 0; j < 4; ++j) {
    int n = 2 * tid + j * 512;
    float2 bv = ld2(b1 + n);
#pragma unroll
    for (int r = 0; r < 4; ++r) {
      float r0 = acc[r][2 * j] + bv.x;
      float r1 = acc[r][2 * j + 1] + bv.y;
      hrow[r][n] = r0 > 0.f ? r0 : 0.f;
      hrow[r][n + 1] = r1 > 0.f ? r1 : 0.f;
    }
  }
  __syncthreads();
  int n0 = 2 * tid;
  float y0[4] = {}, y1[4] = {};
#pragma unroll 2
  for (int k = 0; k < 2048; ++k) {
    float2 wv = ld2(W2 + (size_t)k * 512 + n0);
#pragma unroll
    for (int r = 0; r < 4; ++r) {
      y0[r] = fmaf(hrow[r][k], wv.x, y0[r]);
      y1[r] = fmaf(hrow[r][k], wv.y, y1[r]);
    }
  }
  float2 bv2 = ld2(b2 + n0);
  float x0[4], x1[4];
#pragma unroll
  for (int r = 0; r < 4; ++r) {
    float t0 = y0[r] + bv2.x; t0 = t0 > 0.f ? t0 : 0.f;
    float t1 = y1[r] + bv2.y; t1 = t1 > 0.f ? t1 : 0.f;
    x0[r] = xrow[r][n0] + t0;
    x1[r] = xrow[r][n0 + 1] + t1;
  }
  int lane = tid & 63, wid = tid >> 6;
  float s[4];
#pragma unroll
  for (int r = 0; r < 4; ++r) s[r] = x0[r] + x1[r];
#pragma unroll
  for (int off = 32; off >= 1; off >>= 1)
#pragma unroll
    for (int r = 0; r < 4; ++r) s[r] += __shfl_xor(s[r], off);
  if (lane == 0) {
#pragma unroll
    for (int r = 0; r < 4; ++r) red[r][wid] = s[r];
  }
  __syncthreads();
  float mu[4];
#pragma unroll
  for (int r = 0; r < 4; ++r) mu[r] = (red[r][0] + red[r][1] + red[r][2] + red[r][3]) * (1.0f / 512.0f);
  __syncthreads();
  float d0[4], d1[4];
#pragma unroll
  for (int r = 0; r < 4; ++r) {
    d0[r] = x0[r] - mu[r];
    d1[r] = x1[r] - mu[r];
    s[r] = d0[r] * d0[r] + d1[r] * d1[r];
  }
#pragma unroll
  for (int off = 32; off >= 1; off >>= 1)
#pragma unroll
    for (int r = 0; r < 4; ++r) s[r] += __shfl_xor(s[r], off);
  if (lane == 0) {
#pragma unroll
    for (int r = 0; r < 4; ++r) red[r][wid] = s[r];
  }
  __syncthreads();
  float2 gv = ld2(g + n0);
  float2 btv = ld2(bt + n0);
#pragma unroll
  for (int r = 0; r < 4; ++r) {
    float rstd = 1.0f / sqrtf((red[r][0] + red[r][1] + red[r][2] + red[r][3]) * (1.0f / 512.0f) + 1e-5f);
    st2(out + (size_t)(m0 + r) * 512 + n0, d0[r] * rstd * gv.x + btv.x, d1[r] * rstd * gv.y + btv.y);
  }
}

extern "C" void kernel_launch(void* const* d_in, const int* in_sizes, int n_in,
                              void* d_out, int out_size, void* d_ws, size_t ws_size,
                              hipStream_t stream) {
  // element offsets into d_out (same for either dtype)
  const size_t OFF_X = 0, OFF_ATT = 2097152, OFF_REL = 35651584, OFF_BEMB = 102760448;

  float* outf = (float*)d_out;
  bf16*  outb = (bf16*)d_out;

  // Scratch: inside the rel_emb region under BOTH dtype interpretations.
  // fp32: rel region = bytes [142606336, 411041792)  -> scratch 40MB fits
  // bf16: rel region = bytes [71303168, 205520896)   -> scratch at 142.6MB +40MB fits
  float* scratch = (float*)((char*)d_out + 142606336);
  float* qn   = scratch;
  float* kn   = qn + 2097152;
  float* vvp  = kn + 2097152;
  float* ctx  = vvp + 2097152;
  float* xln1 = ctx + 2097152;

  detect_kernel<<<1, 256, 0, stream>>>((const unsigned int*)d_in[1]);

#define ARGS_BEMB(T, OP) (const T*)d_in[2], (const T*)d_in[12], (const T*)d_in[13], (const T*)d_in[14], OP + OFF_BEMB
  rpe_bemb_kernel<bf16><<<dim3((B_ * NT_ * NS_) / 256), 256, 0, stream>>>(ARGS_BEMB(bf16, outb));
  rpe_bemb_kernel<float><<<dim3((B_ * NT_ * NS_) / 256), 256, 0, stream>>>(ARGS_BEMB(float, outf));

#define ARGS_Q(T) (const T*)d_in[1], (const T*)d_in[3], (const T*)d_in[4], (const T*)d_in[11], qn, 2
#define ARGS_K(T) (const T*)d_in[0], (const T*)d_in[5], (const T*)d_in[6], (const T*)d_in[11], kn, 1
#define ARGS_V(T) (const T*)d_in[0], (const T*)d_in[7], (const T*)d_in[8], (const T*)d_in[11], vvp, 0
  proj_kernel<bf16><<<dim3(B_ * NT_ / 4), 256, 0, stream>>>(ARGS_Q(bf16));
  proj_kernel<float><<<dim3(B_ * NT_ / 4), 256, 0, stream>>>(ARGS_Q(float));
  proj_kernel<bf16><<<dim3(B_ * NS_ / 4), 256, 0, stream>>>(ARGS_K(bf16));
  proj_kernel<float><<<dim3(B_ * NS_ / 4), 256, 0, stream>>>(ARGS_K(float));
  proj_kernel<bf16><<<dim3(B_ * NS_ / 4), 256, 0, stream>>>(ARGS_V(bf16));
  proj_kernel<float><<<dim3(B_ * NS_ / 4), 256, 0, stream>>>(ARGS_V(float));

  attn_kernel<bf16><<<dim3(NT_ / 16, H_, B_), 256, 0, stream>>>(qn, kn, vvp, outb + OFF_BEMB, outb + OFF_ATT, ctx);
  attn_kernel<float><<<dim3(NT_ / 16, H_, B_), 256, 0, stream>>>(qn, kn, vvp, outf + OFF_BEMB, outf + OFF_ATT, ctx);

#define ARGS_O(T) ctx, (const T*)d_in[9], (const T*)d_in[10], (const T*)d_in[1], (const T*)d_in[15], (const T*)d_in[16], xln1
  oproj_ln<bf16><<<dim3(B_ * NT_ / 4), 256, 0, stream>>>(ARGS_O(bf16));
  oproj_ln<float><<<dim3(B_ * NT_ / 4), 256, 0, stream>>>(ARGS_O(float));

#define ARGS_M(T, OP) xln1, (const T*)d_in[17], (const T*)d_in[18], (const T*)d_in[19], (const T*)d_in[20], (const T*)d_in[21], (const T*)d_in[22], OP + OFF_X
  mlp_fused<bf16><<<dim3(B_ * NT_ / 4), 256, 0, stream>>>(ARGS_M(bf16, outb));
  mlp_fused<float><<<dim3(B_ * NT_ / 4), 256, 0, stream>>>(ARGS_M(float, outf));

  // LAST: rel_emb overwrites the scratch region
#define ARGS_REL(T, OP) (const T*)d_in[2], (const T*)d_in[12], (const T*)d_in[13], OP + OFF_REL
  rpe_rel_kernel<bf16><<<dim3((B_ * NT_ * NS_) / 256), 256, 0, stream>>>(ARGS_REL(bf16, outb));
  rpe_rel_kernel<float><<<dim3((B_ * NT_ * NS_) / 256), 256, 0, stream>>>(ARGS_REL(float, outf));
}

// Round 2
// 1484.197 us; speedup vs baseline: 4.0234x; 1.6349x over previous
//
#include <hip/hip_runtime.h>
#include <hip/hip_bf16.h>

typedef __hip_bfloat16 bf16;

#define B_  4
#define NT_ 1024
#define NS_ 1024
#define D_  512
#define E_  512
#define H_  8
#define HD_ 64
#define FF_ 2048
#define RH_ 16

__device__ int g_flag;   // 0 = bf16 tensors, 1 = fp32 tensors

__device__ __forceinline__ float b2f(bf16 x) { return __bfloat162float(x); }

__device__ __forceinline__ float2 upair(unsigned int u) {
  union { unsigned int i; float f; } lo, hi;
  lo.i = u << 16;
  hi.i = u & 0xffff0000u;
  return make_float2(lo.f, hi.f);
}

__device__ __forceinline__ unsigned short f2b_bits(float f) {
  union { bf16 h; unsigned short s; } u;
  u.h = __float2bfloat16(f);
  return u.s;
}

__device__ __forceinline__ unsigned int packbf(float a, float b) {
  return (unsigned int)f2b_bits(a) | ((unsigned int)f2b_bits(b) << 16);
}

template <typename T> struct TypeTag;
template <> struct TypeTag<float> { static constexpr int v = 1; };
template <> struct TypeTag<bf16>  { static constexpr int v = 0; };

template <typename T> __device__ __forceinline__ float ld1(const T* p);
template <> __device__ __forceinline__ float ld1<float>(const float* p) { return *p; }
template <> __device__ __forceinline__ float ld1<bf16>(const bf16* p) { return b2f(*p); }

template <typename T> __device__ __forceinline__ float2 ld2(const T* p);
template <> __device__ __forceinline__ float2 ld2<float>(const float* p) { return *(const float2*)p; }
template <> __device__ __forceinline__ float2 ld2<bf16>(const bf16* p) { return upair(*(const unsigned int*)p); }

template <typename T> __device__ __forceinline__ void st2(T* p, float a, float b);
template <> __device__ __forceinline__ void st2<float>(float* p, float a, float b) { *(float2*)p = make_float2(a, b); }
template <> __device__ __forceinline__ void st2<bf16>(bf16* p, float a, float b) { *(unsigned int*)p = packbf(a, b); }

// 4 consecutive elements -> float4
template <typename T> __device__ __forceinline__ float4 ld4(const T* p);
template <> __device__ __forceinline__ float4 ld4<float>(const float* p) { return *(const float4*)p; }
template <> __device__ __forceinline__ float4 ld4<bf16>(const bf16* p) {
  uint2 u = *(const uint2*)p;
  float2 a = upair(u.x), b = upair(u.y);
  return make_float4(a.x, a.y, b.x, b.y);
}

template <typename T> __device__ __forceinline__ void st4(T* p, float4 v);
template <> __device__ __forceinline__ void st4<float>(float* p, float4 v) { *(float4*)p = v; }
template <> __device__ __forceinline__ void st4<bf16>(bf16* p, float4 v) {
  *(uint2*)p = make_uint2(packbf(v.x, v.y), packbf(v.z, v.w));
}

// 8 consecutive elements -> float[8]
__device__ __forceinline__ void ld8(const float* p, float* r) {
  float4 a = *(const float4*)p, b = *(const float4*)(p + 4);
  r[0] = a.x; r[1] = a.y; r[2] = a.z; r[3] = a.w;
  r[4] = b.x; r[5] = b.y; r[6] = b.z; r[7] = b.w;
}
__device__ __forceinline__ void ld8(const bf16* p, float* r) {
  uint4 u = *(const uint4*)p;
  float2 a = upair(u.x), b = upair(u.y), c = upair(u.z), d = upair(u.w);
  r[0] = a.x; r[1] = a.y; r[2] = b.x; r[3] = b.y;
  r[4] = c.x; r[5] = c.y; r[6] = d.x; r[7] = d.y;
}

// ---- detector: fp32 inputs leave random-exponent garbage when read as bf16 ---
__global__ void detect_kernel(const unsigned int* __restrict__ xt_raw) {
  __shared__ int bad;
  if (threadIdx.x == 0) bad = 0;
  __syncthreads();
  int t = threadIdx.x;
  int local = 0;
  for (int i = 0; i < 8; ++i) {
    float2 v = upair(xt_raw[t * 8 + i]);
    if (!(fabsf(v.x) <= 1e8f)) local = 1;
    if (!(fabsf(v.y) <= 1e8f)) local = 1;
  }
  if (local) atomicOr(&bad, 1);
  __syncthreads();
  if (t == 0) g_flag = bad;
}

// ---------------- RPE part 1: b_emb (needed by attention) ---------------------
template <typename T>
__global__ void rpe_bemb_kernel(const T* __restrict__ coords,
                                const T* __restrict__ W1, const T* __restrict__ b1,
                                const T* __restrict__ W2, T* __restrict__ b_emb) {
  if (g_flag != TypeTag<T>::v) return;
  __shared__ float sW1[32], sb1[16], sW2[128];
  int tid = threadIdx.x;
  if (tid < 32)  sW1[tid] = ld1(W1 + tid);
  if (tid < 16)  sb1[tid] = ld1(b1 + tid);
  if (tid < 128) sW2[tid] = ld1(W2 + tid);
  __syncthreads();
  size_t idx = (size_t)blockIdx.x * 256 + tid;
  float2 c = ld2(coords + idx * 2);
  float h[16];
#pragma unroll
  for (int j = 0; j < 16; ++j) {
    float t = fmaf(c.x, sW1[j], fmaf(c.y, sW1[16 + j], sb1[j]));
    h[j] = t > 0.f ? t : 0.f;
  }
  float acc[8] = {0.f, 0.f, 0.f, 0.f, 0.f, 0.f, 0.f, 0.f};
#pragma unroll
  for (int j = 0; j < 16; ++j) {
    float hv = h[j];
#pragma unroll
    for (int n = 0; n < 8; ++n) acc[n] = fmaf(hv, sW2[j * 8 + n], acc[n]);
  }
  T* bp = b_emb + idx * 8;
#pragma unroll
  for (int j = 0; j < 4; ++j) st2(bp + 2 * j, acc[2 * j], acc[2 * j + 1]);
}

// ---------------- RPE part 2: rel_emb (runs LAST; overwrites scratch) ---------
template <typename T>
__global__ void rpe_rel_kernel(const T* __restrict__ coords,
                               const T* __restrict__ W1, const T* __restrict__ b1,
                               T* __restrict__ rel_emb) {
  if (g_flag != TypeTag<T>::v) return;
  __shared__ float sW1[32], sb1[16];
  int tid = threadIdx.x;
  if (tid < 32)  sW1[tid] = ld1(W1 + tid);
  if (tid < 16)  sb1[tid] = ld1(b1 + tid);
  __syncthreads();
  size_t idx = (size_t)blockIdx.x * 256 + tid;
  float2 c = ld2(coords + idx * 2);
  T* rp = rel_emb + idx * 16;
#pragma unroll
  for (int j = 0; j < 16; j += 2) {
    float t0 = fmaf(c.x, sW1[j], fmaf(c.y, sW1[16 + j], sb1[j]));
    float t1 = fmaf(c.x, sW1[j + 1], fmaf(c.y, sW1[16 + j + 1], sb1[j + 1]));
    st2(rp + j, t0 > 0.f ? t0 : 0.f, t1 > 0.f ? t1 : 0.f);
  }
}

// ---------------- tiled 64x64 GEMM, BK=32, 4x4 micro-tile ---------------------
// C[M,N] = A[M,K] @ W[K,Nw] (tile at n0=blockIdx.y*64) + bias, with epilogue:
// EPI 0: +bias           -> fp32 row-major outF[M][Nw]        (oproj)
// EPI 1: +bias, relu     -> fp32 row-major outF[M][Nw]        (mlp2)
// EPI 2: +bias, relu     -> bf16 row-major outB[M][Nw]        (mlp1 -> H)
// EPI 3: +bias, per-head normalize (mode: 0=v,1=k,2=q) -> permuted fp32 [B,H,N,64]
template <typename TA, typename TW, int EPI>
__global__ __launch_bounds__(256) void gemm64(
    const TA* __restrict__ A, const TW* __restrict__ W, const TW* __restrict__ bias,
    const TW* __restrict__ lsc, int mode, int K, int Nw,
    float* __restrict__ outF, bf16* __restrict__ outB) {
  if (g_flag != TypeTag<TW>::v) return;
  __shared__ float sA[2][32][64];
  __shared__ float sB[2][32][64];
  int tid = threadIdx.x;
  int m0 = blockIdx.x * 64, n0 = blockIdx.y * 64;
  int T = K >> 5;

  // staging coords
  int ar = tid >> 2, ac = (tid & 3) * 8;   // A tile: row ar (0..63), col ac (0,8,16,24)
  int wr = tid >> 3, wc = (tid & 7) * 8;   // W tile: krow wr (0..31), col wc (0..56)
  const TA* Ap = A + (size_t)(m0 + ar) * K + ac;
  const TW* Wp = W + (size_t)wr * Nw + n0 + wc;

  float ra[8], rw[8];
  // tile 0 -> buf0
  ld8(Ap, ra);
  ld8(Wp, rw);
#pragma unroll
  for (int u = 0; u < 8; ++u) sA[0][ac + u][ar] = ra[u];
#pragma unroll
  for (int u = 0; u < 8; ++u) sB[0][wr][wc + u] = rw[u];
  // tile 1 -> regs
  if (T > 1) {
    ld8(Ap + 32, ra);
    ld8(Wp + (size_t)32 * Nw, rw);
  }
  __syncthreads();

  int tx = tid & 15, ty = tid >> 4;
  float acc[4][4] = {};
  for (int t = 0; t < T; ++t) {
    int cur = t & 1, nxt = cur ^ 1;
    if (t + 1 < T) {
#pragma unroll
      for (int u = 0; u < 8; ++u) sA[nxt][ac + u][ar] = ra[u];
#pragma unroll
      for (int u = 0; u < 8; ++u) sB[nxt][wr][wc + u] = rw[u];
    }
    if (t + 2 < T) {
      ld8(Ap + (t + 2) * 32, ra);
      ld8(Wp + (size_t)(t + 2) * 32 * Nw, rw);
    }
#pragma unroll 8
    for (int kk = 0; kk < 32; ++kk) {
      float4 av = *(const float4*)&sA[cur][kk][ty * 4];
      float4 bv = *(const float4*)&sB[cur][kk][tx * 4];
      acc[0][0] = fmaf(av.x, bv.x, acc[0][0]);
      acc[0][1] = fmaf(av.x, bv.y, acc[0][1]);
      acc[0][2] = fmaf(av.x, bv.z, acc[0][2]);
      acc[0][3] = fmaf(av.x, bv.w, acc[0][3]);
      acc[1][0] = fmaf(av.y, bv.x, acc[1][0]);
      acc[1][1] = fmaf(av.y, bv.y, acc[1][1]);
      acc[1][2] = fmaf(av.y, bv.z, acc[1][2]);
      acc[1][3] = fmaf(av.y, bv.w, acc[1][3]);
      acc[2][0] = fmaf(av.z, bv.x, acc[2][0]);
      acc[2][1] = fmaf(av.z, bv.y, acc[2][1]);
      acc[2][2] = fmaf(av.z, bv.z, acc[2][2]);
      acc[2][3] = fmaf(av.z, bv.w, acc[2][3]);
      acc[3][0] = fmaf(av.w, bv.x, acc[3][0]);
      acc[3][1] = fmaf(av.w, bv.y, acc[3][1]);
      acc[3][2] = fmaf(av.w, bv.z, acc[3][2]);
      acc[3][3] = fmaf(av.w, bv.w, acc[3][3]);
    }
    __syncthreads();
  }

  // epilogue
  float2 b01 = ld2(bias + n0 + tx * 4);
  float2 b23 = ld2(bias + n0 + tx * 4 + 2);
  float bs[4] = {b01.x, b01.y, b23.x, b23.y};
#pragma unroll
  for (int i = 0; i < 4; ++i)
#pragma unroll
    for (int j = 0; j < 4; ++j) {
      acc[i][j] += bs[j];
      if (EPI == 1 || EPI == 2) acc[i][j] = acc[i][j] > 0.f ? acc[i][j] : 0.f;
    }

  if (EPI == 0 || EPI == 1) {
#pragma unroll
    for (int i = 0; i < 4; ++i) {
      int m = m0 + ty * 4 + i;
      *(float4*)&outF[(size_t)m * Nw + n0 + tx * 4] =
          make_float4(acc[i][0], acc[i][1], acc[i][2], acc[i][3]);
    }
  } else if (EPI == 2) {
#pragma unroll
    for (int i = 0; i < 4; ++i) {
      int m = m0 + ty * 4 + i;
      *(uint2*)(outB + (size_t)m * Nw + n0 + tx * 4) =
          make_uint2(packbf(acc[i][0], acc[i][1]), packbf(acc[i][2], acc[i][3]));
    }
  } else {  // EPI 3: qkv with per-head normalize; head h = blockIdx.y
    float r[4] = {1.f, 1.f, 1.f, 1.f};
    if (mode > 0) {
      float s[4];
#pragma unroll
      for (int i = 0; i < 4; ++i)
        s[i] = acc[i][0] * acc[i][0] + acc[i][1] * acc[i][1] +
               acc[i][2] * acc[i][2] + acc[i][3] * acc[i][3];
#pragma unroll
      for (int off = 8; off >= 1; off >>= 1)
#pragma unroll
        for (int i = 0; i < 4; ++i) s[i] += __shfl_xor(s[i], off);
      float ls = 1.f;
      if (mode == 2) ls = expf(fminf(ld1(lsc + blockIdx.y), 4.60517018598809f));
#pragma unroll
      for (int i = 0; i < 4; ++i) r[i] = ls / sqrtf(s[i] + 1e-12f);
    }
#pragma unroll
    for (int i = 0; i < 4; ++i) {
      int m = m0 + ty * 4 + i;
      int b = m >> 10, row = m & 1023;
      float* op = outF + (((size_t)(b * H_ + blockIdx.y)) * 1024 + row) * 64 + tx * 4;
      *(float4*)op = make_float4(acc[i][0] * r[i], acc[i][1] * r[i],
                                 acc[i][2] * r[i], acc[i][3] * r[i]);
    }
  }
}

// ---------------- LN kernels: wave per row, 4 rows per block ------------------
// ln1: x = LN(xt(T) + Y(fp32)) -> fp32 out
template <typename T>
__global__ __launch_bounds__(256) void ln1_kernel(const T* __restrict__ xt,
                                                  const float* __restrict__ Y,
                                                  const T* __restrict__ g, const T* __restrict__ bt,
                                                  float* __restrict__ out) {
  if (g_flag != TypeTag<T>::v) return;
  int lane = threadIdx.x & 63, wid = threadIdx.x >> 6;
  size_t row = (size_t)blockIdx.x * 4 + wid;
  int c0 = lane * 4, c1 = 256 + lane * 4;
  float4 y0 = *(const float4*)(Y + row * 512 + c0);
  float4 y1 = *(const float4*)(Y + row * 512 + c1);
  float4 t0 = ld4(xt + row * 512 + c0);
  float4 t1 = ld4(xt + row * 512 + c1);
  float x0[4] = {t0.x + y0.x, t0.y + y0.y, t0.z + y0.z, t0.w + y0.w};
  float x1[4] = {t1.x + y1.x, t1.y + y1.y, t1.z + y1.z, t1.w + y1.w};
  float s = 0.f;
#pragma unroll
  for (int j = 0; j < 4; ++j) s += x0[j] + x1[j];
#pragma unroll
  for (int off = 32; off >= 1; off >>= 1) s += __shfl_xor(s, off);
  float mu = s * (1.0f / 512.0f);
  float v = 0.f;
#pragma unroll
  for (int j = 0; j < 4; ++j) {
    x0[j] -= mu; x1[j] -= mu;
    v += x0[j] * x0[j] + x1[j] * x1[j];
  }
#pragma unroll
  for (int off = 32; off >= 1; off >>= 1) v += __shfl_xor(v, off);
  float rstd = 1.0f / sqrtf(v * (1.0f / 512.0f) + 1e-5f);
  float4 g0 = ld4(g + c0), g1 = ld4(g + c1);
  float4 bb0 = ld4(bt + c0), bb1 = ld4(bt + c1);
  *(float4*)(out + row * 512 + c0) = make_float4(
      x0[0] * rstd * g0.x + bb0.x, x0[1] * rstd * g0.y + bb0.y,
      x0[2] * rstd * g0.z + bb0.z, x0[3] * rstd * g0.w + bb0.w);
  *(float4*)(out + row * 512 + c1) = make_float4(
      x1[0] * rstd * g1.x + bb1.x, x1[1] * rstd * g1.y + bb1.y,
      x1[2] * rstd * g1.z + bb1.z, x1[3] * rstd * g1.w + bb1.w);
}

// ln2: x = LN(xres(fp32) + Y(fp32)) -> T out
template <typename T>
__global__ __launch_bounds__(256) void ln2_kernel(const float* __restrict__ xres,
                                                  const float* __restrict__ Y,
                                                  const T* __restrict__ g, const T* __restrict__ bt,
                                                  T* __restrict__ out) {
  if (g_flag != TypeTag<T>::v) return;
  int lane = threadIdx.x & 63, wid = threadIdx.x >> 6;
  size_t row = (size_t)blockIdx.x * 4 + wid;
  int c0 = lane * 4, c1 = 256 + lane * 4;
  float4 y0 = *(const float4*)(Y + row * 512 + c0);
  float4 y1 = *(const float4*)(Y + row * 512 + c1);
  float4 t0 = *(const float4*)(xres + row * 512 + c0);
  float4 t1 = *(const float4*)(xres + row * 512 + c1);
  float x0[4] = {t0.x + y0.x, t0.y + y0.y, t0.z + y0.z, t0.w + y0.w};
  float x1[4] = {t1.x + y1.x, t1.y + y1.y, t1.z + y1.z, t1.w + y1.w};
  float s = 0.f;
#pragma unroll
  for (int j = 0; j < 4; ++j) s += x0[j] + x1[j];
#pragma unroll
  for (int off = 32; off >= 1; off >>= 1) s += __shfl_xor(s, off);
  float mu = s * (1.0f / 512.0f);
  float v = 0.f;
#pragma unroll
  for (int j = 0; j < 4; ++j) {
    x0[j] -= mu; x1[j] -= mu;
    v += x0[j] * x0[j] + x1[j] * x1[j];
  }
#pragma unroll
  for (int off = 32; off >= 1; off >>= 1) v += __shfl_xor(v, off);
  float rstd = 1.0f / sqrtf(v * (1.0f / 512.0f) + 1e-5f);
  float4 g0 = ld4(g + c0), g1 = ld4(g + c1);
  float4 bb0 = ld4(bt + c0), bb1 = ld4(bt + c1);
  st4(out + row * 512 + c0, make_float4(
      x0[0] * rstd * g0.x + bb0.x, x0[1] * rstd * g0.y + bb0.y,
      x0[2] * rstd * g0.z + bb0.z, x0[3] * rstd * g0.w + bb0.w));
  st4(out + row * 512 + c1, make_float4(
      x1[0] * rstd * g1.x + bb1.x, x1[1] * rstd * g1.y + bb1.y,
      x1[2] * rstd * g1.z + bb1.z, x1[3] * rstd * g1.w + bb1.w));
}

// ---------------- attention: one block per (b,h, 16-q-row tile) ---------------
// LDS: sc[16][1024] score tile (64KB); Q tile aliases sc[0..1023] during QK.
template <typename T>
__global__ void attn_kernel(const float* __restrict__ qn, const float* __restrict__ kn,
                            const float* __restrict__ vv, const T* __restrict__ bemb,
                            T* __restrict__ att, float* __restrict__ ctx) {
  if (g_flag != TypeTag<T>::v) return;
  __shared__ float sc[16 * 1024];
  int tid = threadIdx.x;
  int qt0 = blockIdx.x * 16;
  int h = blockIdx.y, b = blockIdx.z;
  size_t bh = (size_t)b * H_ + h;

  // phase 1: Q tile (16 rows x 64) -> sc[0..1023]
  {
    const float4* qp = (const float4*)(qn + (bh * 1024 + qt0) * 64);
    ((float4*)sc)[tid] = qp[tid];
  }
  __syncthreads();

  // phase 2: scores. thread owns k in {tid, tid+256, tid+512, tid+768}
  float acc[16][4];
#pragma unroll
  for (int q = 0; q < 16; ++q)
#pragma unroll
    for (int i = 0; i < 4; ++i) acc[q][i] = 0.f;
  const float* kb = kn + bh * 65536;
#pragma unroll 4
  for (int dc = 0; dc < 16; ++dc) {
    float4 kv[4];
#pragma unroll
    for (int i = 0; i < 4; ++i)
      kv[i] = *(const float4*)(kb + (size_t)(tid + 256 * i) * 64 + dc * 4);
#pragma unroll
    for (int q = 0; q < 16; ++q) {
      float4 qv = *(const float4*)(sc + q * 64 + dc * 4);  // broadcast
#pragma unroll
      for (int i = 0; i < 4; ++i) {
        acc[q][i] = fmaf(qv.x, kv[i].x, acc[q][i]);
        acc[q][i] = fmaf(qv.y, kv[i].y, acc[q][i]);
        acc[q][i] = fmaf(qv.z, kv[i].z, acc[q][i]);
        acc[q][i] = fmaf(qv.w, kv[i].w, acc[q][i]);
      }
    }
  }
  // add b_emb
  {
    const T* bb = bemb + ((size_t)(b * 1024 + qt0) * 1024) * 8 + h;
#pragma unroll
    for (int q = 0; q < 16; ++q)
#pragma unroll
      for (int i = 0; i < 4; ++i)
        acc[q][i] += ld1(bb + ((size_t)q * 1024 + tid + 256 * i) * 8);
  }
  __syncthreads();  // all Q reads done; overwrite sc with scores
#pragma unroll
  for (int q = 0; q < 16; ++q)
#pragma unroll
    for (int i = 0; i < 4; ++i) sc[q * 1024 + tid + 256 * i] = acc[q][i];
  __syncthreads();

  // phase 3: row softmax. 16 threads per row, shfl reductions (same wave).
  {
    int r = tid >> 4, j = tid & 15;
    float* srow = sc + r * 1024;
    float mx = -1e30f;
#pragma unroll 8
    for (int m = 0; m < 64; ++m) mx = fmaxf(mx, srow[j + 16 * m]);
#pragma unroll
    for (int off = 8; off >= 1; off >>= 1) mx = fmaxf(mx, __shfl_xor(mx, off));
    float sum = 0.f;
#pragma unroll 8
    for (int m = 0; m < 64; ++m) {
      float p = __expf(srow[j + 16 * m] - mx);
      srow[j + 16 * m] = p;
      sum += p;
    }
#pragma unroll
    for (int off = 8; off >= 1; off >>= 1) sum += __shfl_xor(sum, off);
    float inv = 1.0f / sum;
#pragma unroll 8
    for (int m = 0; m < 64; ++m) srow[j + 16 * m] *= inv;
  }
  __syncthreads();

  // phase 4a: write att tile (coalesced pair stores)
  {
    T* ap = att + (bh * 1024 + qt0) * 1024;
#pragma unroll
    for (int w = 0; w < 32; ++w) {
      int f = 2 * (w * 256 + tid);
      float2 pv = *(const float2*)(sc + f);
      st2(ap + f, pv.x, pv.y);
    }
  }

  // phase 4b: PV. wave gq owns q rows 4*gq..4*gq+3; lane owns d.
  {
    int d = tid & 63, gq = tid >> 6;
    const float* vb = vv + bh * 65536;
    const float* p0 = sc + (4 * gq + 0) * 1024;
    const float* p1 = sc + (4 * gq + 1) * 1024;
    const float* p2 = sc + (4 * gq + 2) * 1024;
    const float* p3 = sc + (4 * gq + 3) * 1024;
    float a0 = 0.f, a1 = 0.f, a2 = 0.f, a3 = 0.f;
    for (int k = 0; k < 1024; k += 4) {
      float4 q0 = *(const float4*)(p0 + k);
      float4 q1 = *(const float4*)(p1 + k);
      float4 q2 = *(const float4*)(p2 + k);
      float4 q3 = *(const float4*)(p3 + k);
      float v0 = vb[(size_t)(k + 0) * 64 + d];
      float v1 = vb[(size_t)(k + 1) * 64 + d];
      float v2 = vb[(size_t)(k + 2) * 64 + d];
      float v3 = vb[(size_t)(k + 3) * 64 + d];
      a0 = fmaf(q0.w, v3, fmaf(q0.z, v2, fmaf(q0.y, v1, fmaf(q0.x, v0, a0))));
      a1 = fmaf(q1.w, v3, fmaf(q1.z, v2, fmaf(q1.y, v1, fmaf(q1.x, v0, a1))));
      a2 = fmaf(q2.w, v3, fmaf(q2.z, v2, fmaf(q2.y, v1, fmaf(q2.x, v0, a2))));
      a3 = fmaf(q3.w, v3, fmaf(q3.z, v2, fmaf(q3.y, v1, fmaf(q3.x, v0, a3))));
    }
    float* cb = ctx + ((size_t)b * 1024 + qt0 + 4 * gq) * 512 + h * 64 + d;
    cb[0] = a0;
    cb[512] = a1;
    cb[1024] = a2;
    cb[1536] = a3;
  }
}

extern "C" void kernel_launch(void* const* d_in, const int* in_sizes, int n_in,
                              void* d_out, int out_size, void* d_ws, size_t ws_size,
                              hipStream_t stream) {
  // element offsets into d_out (same for either dtype)
  const size_t OFF_X = 0, OFF_ATT = 2097152, OFF_REL = 35651584, OFF_BEMB = 102760448;

  float* outf = (float*)d_out;
  bf16*  outb = (bf16*)d_out;

  // Scratch inside the rel_emb region under BOTH dtype interpretations:
  // intersection = bytes [142606336, 205520896) -> 60MB budget.
  float* scratch = (float*)((char*)d_out + 142606336);
  float* qn   = scratch;            // 8MB
  float* kn   = qn + 2097152;       // 8MB
  float* vvp  = kn + 2097152;       // 8MB
  float* ctx  = vvp + 2097152;      // 8MB
  float* xln1 = ctx + 2097152;      // 8MB  (ends at +40MB)
  float* Y    = xln1 + 2097152;     // fp32 8MB  [oproj out; consumed by ln1]
  bf16*  Hb   = (bf16*)Y;           // bf16 16MB [mlp1 out; written AFTER ln1]  ends +56MB
  float* Y2   = ctx;                // reuse ctx region after oproj [mlp2 out]

  detect_kernel<<<1, 256, 0, stream>>>((const unsigned int*)d_in[1]);

#define ARGS_BEMB(T, OP) (const T*)d_in[2], (const T*)d_in[12], (const T*)d_in[13], (const T*)d_in[14], OP + OFF_BEMB
  rpe_bemb_kernel<bf16><<<dim3((B_ * NT_ * NS_) / 256), 256, 0, stream>>>(ARGS_BEMB(bf16, outb));
  rpe_bemb_kernel<float><<<dim3((B_ * NT_ * NS_) / 256), 256, 0, stream>>>(ARGS_BEMB(float, outf));

  // q/k/v projections with fused per-head normalize (EPI 3)
#define LAUNCH_QKV(T) \
  gemm64<T, T, 3><<<dim3(64, 8), 256, 0, stream>>>((const T*)d_in[1], (const T*)d_in[3], (const T*)d_in[4], (const T*)d_in[11], 2, 512, 512, qn, nullptr); \
  gemm64<T, T, 3><<<dim3(64, 8), 256, 0, stream>>>((const T*)d_in[0], (const T*)d_in[5], (const T*)d_in[6], (const T*)d_in[11], 1, 512, 512, kn, nullptr); \
  gemm64<T, T, 3><<<dim3(64, 8), 256, 0, stream>>>((const T*)d_in[0], (const T*)d_in[7], (const T*)d_in[8], (const T*)d_in[11], 0, 512, 512, vvp, nullptr);
  LAUNCH_QKV(bf16)
  LAUNCH_QKV(float)

  attn_kernel<bf16><<<dim3(NT_ / 16, H_, B_), 256, 0, stream>>>(qn, kn, vvp, outb + OFF_BEMB, outb + OFF_ATT, ctx);
  attn_kernel<float><<<dim3(NT_ / 16, H_, B_), 256, 0, stream>>>(qn, kn, vvp, outf + OFF_BEMB, outf + OFF_ATT, ctx);

  // out-proj -> Y; then LN1 -> xln1
  gemm64<float, bf16, 0><<<dim3(64, 8), 256, 0, stream>>>(ctx, (const bf16*)d_in[9], (const bf16*)d_in[10], nullptr, 0, 512, 512, Y, nullptr);
  gemm64<float, float, 0><<<dim3(64, 8), 256, 0, stream>>>(ctx, (const float*)d_in[9], (const float*)d_in[10], nullptr, 0, 512, 512, Y, nullptr);
  ln1_kernel<bf16><<<dim3(1024), 256, 0, stream>>>((const bf16*)d_in[1], Y, (const bf16*)d_in[15], (const bf16*)d_in[16], xln1);
  ln1_kernel<float><<<dim3(1024), 256, 0, stream>>>((const float*)d_in[1], Y, (const float*)d_in[15], (const float*)d_in[16], xln1);

  // MLP: xln1 @ W1 -> H (bf16, relu); H @ W2 -> Y2 (relu); LN2 -> out
  gemm64<float, bf16, 2><<<dim3(64, 32), 256, 0, stream>>>(xln1, (const bf16*)d_in[17], (const bf16*)d_in[18], nullptr, 0, 512, 2048, nullptr, Hb);
  gemm64<float, float, 2><<<dim3(64, 32), 256, 0, stream>>>(xln1, (const float*)d_in[17], (const float*)d_in[18], nullptr, 0, 512, 2048, nullptr, Hb);
  gemm64<bf16, bf16, 1><<<dim3(64, 8), 256, 0, stream>>>(Hb, (const bf16*)d_in[19], (const bf16*)d_in[20], nullptr, 0, 2048, 512, Y2, nullptr);
  gemm64<bf16, float, 1><<<dim3(64, 8), 256, 0, stream>>>(Hb, (const float*)d_in[19], (const float*)d_in[20], nullptr, 0, 2048, 512, Y2, nullptr);
  ln2_kernel<bf16><<<dim3(1024), 256, 0, stream>>>(xln1, Y2, (const bf16*)d_in[21], (const bf16*)d_in[22], outb + OFF_X);
  ln2_kernel<float><<<dim3(1024), 256, 0, stream>>>(xln1, Y2, (const float*)d_in[21], (const float*)d_in[22], outf + OFF_X);

  // LAST: rel_emb overwrites the scratch region
#define ARGS_REL(T, OP) (const T*)d_in[2], (const T*)d_in[12], (const T*)d_in[13], OP + OFF_REL
  rpe_rel_kernel<bf16><<<dim3((B_ * NT_ * NS_) / 256), 256, 0, stream>>>(ARGS_REL(bf16, outb));
  rpe_rel_kernel<float><<<dim3((B_ * NT_ * NS_) / 256), 256, 0, stream>>>(ARGS_REL(float, outf));
}